// Round 3
// baseline (2032.721 us; speedup 1.0000x reference)
//
#include <hip/hip_runtime.h>

#define NEG 0.01f
__device__ __forceinline__ float lrelu(float v){ return v >= 0.f ? v : NEG * v; }

__device__ __forceinline__ float fma4(float4 wv, float4 hv, float acc) {
  return fmaf(wv.x, hv.x, fmaf(wv.y, hv.y, fmaf(wv.z, hv.z, fmaf(wv.w, hv.w, acc))));
}

// LDS plan (48.5 KB total -> 3 blocks/CU):
// Region R (6912 floats = 27648 B):
//   xs@0(121) [stage0-1] ; sb2@0 [81][36], gb2@2916 [81][36] [stages 2-4a] ; hrow@0 [64][9][12] [stages 4b-5]
// Region H (5508 floats = 22032 B):
//   h2@0 [81][68] ch-major [stages 1-4b] ; then c2s@0 [32][7][8], c3s@1792(200),
//   scratch@1992: c2p(1568) / p6(1600) / d1p(256)+d1(64)+d2(32)+d3(16)+d4(8)
__global__ __launch_bounds__(256, 3) void braggnn_fused(
    const float* __restrict__ x,
    const float* __restrict__ w1, const float* __restrict__ b1,
    const float* __restrict__ wt, const float* __restrict__ bt,
    const float* __restrict__ wp, const float* __restrict__ bp,
    const float* __restrict__ wg, const float* __restrict__ bg,
    const float* __restrict__ wo, const float* __restrict__ bo,
    const float* __restrict__ w2, const float* __restrict__ b2,
    const float* __restrict__ w3, const float* __restrict__ b3,
    const float* __restrict__ dw1, const float* __restrict__ db1,
    const float* __restrict__ dw2, const float* __restrict__ db2,
    const float* __restrict__ dw3, const float* __restrict__ db3,
    const float* __restrict__ dw4, const float* __restrict__ db4,
    const float* __restrict__ dw5, const float* __restrict__ db5,
    float* __restrict__ out)
{
  const int b = blockIdx.x;
  const int t = threadIdx.x;

  __shared__ __align__(16) float R[6912];
  __shared__ __align__(16) float H[5508];

  float* xs   = R;
  float* sb2  = R;            // [81][36]
  float* gb2  = R + 2916;     // [81][36]
  float* hrow = R;            // [64][9][12]
  float* h2   = H;            // [81][68]
  float* c2s  = H;            // [32][7][8]
  float* c3s  = H + 1792;     // 200
  float* c2p  = H + 1992;     // 112*14
  float* p6   = H + 1992;     // 25*64
  float* d1p  = H + 1992;     // 256
  float* d1   = H + 1992 + 256;
  float* d2   = d1 + 64;
  float* d3   = d2 + 32;
  float* d4   = d3 + 16;

  // ---- stage 0: load 11x11 patch ----
  if (t < 121) xs[t] = x[(size_t)b * 121 + t];
  __syncthreads();

  // ---- stage 1: conv1 1->64 3x3 -> h2[px][oc] (ch-major, stride 68), no act ----
  {
    const int oc = t & 63, pg = t >> 6;   // pg = wave index (uniform bound per wave)
    float wreg[9];
#pragma unroll
    for (int i = 0; i < 9; i++) wreg[i] = w1[oc * 9 + i];
    const float bv = b1[oc];
    for (int px = pg; px < 81; px += 4) {
      const int y = px / 9, xx = px - y * 9;
      const float* xr = &xs[y * 11 + xx];
      float a = bv;
#pragma unroll
      for (int ky = 0; ky < 3; ky++)
#pragma unroll
        for (int kx = 0; kx < 3; kx++)
          a = fmaf(xr[ky * 11 + kx], wreg[ky * 3 + kx], a);
      h2[px * 68 + oc] = a;
    }
  }
  __syncthreads();

  // ---- stage 2: theta/phi/g 1x1 (64->32), 2-oc x 6-px blocking, b128 channel reads ----
  {
    const int ocp = t >> 4, q = t & 15;
    const int oc0 = ocp * 2;
    int pxs[6];
#pragma unroll
    for (int j = 0; j < 6; j++) { int p = q + 16 * j; pxs[j] = (p > 80) ? 80 : p; }
    float aT0[6] = {0,0,0,0,0,0}, aT1[6] = {0,0,0,0,0,0};
    float aP0[6] = {0,0,0,0,0,0}, aP1[6] = {0,0,0,0,0,0};
    float aG0[6] = {0,0,0,0,0,0}, aG1[6] = {0,0,0,0,0,0};
    const float4* wt4 = (const float4*)wt;
    const float4* wp4 = (const float4*)wp;
    const float4* wg4 = (const float4*)wg;
    const int r0 = oc0 * 16, r1 = r0 + 16;
#pragma unroll 4
    for (int k4 = 0; k4 < 16; k4++) {
      const float4 wT0 = wt4[r0 + k4], wT1 = wt4[r1 + k4];
      const float4 wP0 = wp4[r0 + k4], wP1 = wp4[r1 + k4];
      const float4 wG0 = wg4[r0 + k4], wG1 = wg4[r1 + k4];
#pragma unroll
      for (int j = 0; j < 6; j++) {
        const float4 hv = *(const float4*)&h2[pxs[j] * 68 + k4 * 4];
        aT0[j] = fma4(wT0, hv, aT0[j]); aT1[j] = fma4(wT1, hv, aT1[j]);
        aP0[j] = fma4(wP0, hv, aP0[j]); aP1[j] = fma4(wP1, hv, aP1[j]);
        aG0[j] = fma4(wG0, hv, aG0[j]); aG1[j] = fma4(wG1, hv, aG1[j]);
      }
    }
    const float bT0 = bt[oc0], bT1 = bt[oc0 + 1];
    const float bP0 = bp[oc0], bP1 = bp[oc0 + 1];
    const float bG0 = bg[oc0], bG1 = bg[oc0 + 1];
#pragma unroll
    for (int j = 0; j < 6; j++) {
      const int base = pxs[j] * 36 + oc0;
      float2 sv, gv;
      sv.x = (aT0[j] + bT0) * (aP0[j] + bP0);
      sv.y = (aT1[j] + bT1) * (aP1[j] + bP1);
      gv.x = aG0[j] + bG0;
      gv.y = aG1[j] + bG1;
      *(float2*)&sb2[base] = sv;   // duplicate px=80 writes carry identical values
      *(float2*)&gb2[base] = gv;
    }
  }
  __syncthreads();

  // ---- stage 3: softmax over W (9), scale gb2 in place ----
  for (int r = t; r < 288; r += 256) {
    const int oc = r & 31, y = r >> 5;
    const int base = y * 9 * 36 + oc;
    float v[9]; float m = -1e30f;
#pragma unroll
    for (int k = 0; k < 9; k++) { v[k] = sb2[base + k * 36]; m = fmaxf(m, v[k]); }
    float s = 0.f;
#pragma unroll
    for (int k = 0; k < 9; k++) { v[k] = __expf(v[k] - m); s += v[k]; }
    const float inv = 1.f / s;
#pragma unroll
    for (int k = 0; k < 9; k++) gb2[base + k * 36] *= v[k] * inv;
  }
  __syncthreads();

  // ---- stage 4: wo 1x1 (32->64) + residual + lrelu; transpose to hrow ----
  {
    const int ocq = t >> 4, q = t & 15;
    const int oc0 = ocq * 4;
    int pxs[6];
#pragma unroll
    for (int j = 0; j < 6; j++) { int p = q + 16 * j; pxs[j] = (p > 80) ? 80 : p; }
    float a0[6] = {0,0,0,0,0,0}, a1[6] = {0,0,0,0,0,0};
    float a2[6] = {0,0,0,0,0,0}, a3[6] = {0,0,0,0,0,0};
    const float4* wo4 = (const float4*)wo;
#pragma unroll 4
    for (int k4 = 0; k4 < 8; k4++) {
      const float4 u0 = wo4[(oc0 + 0) * 8 + k4];
      const float4 u1 = wo4[(oc0 + 1) * 8 + k4];
      const float4 u2 = wo4[(oc0 + 2) * 8 + k4];
      const float4 u3 = wo4[(oc0 + 3) * 8 + k4];
#pragma unroll
      for (int j = 0; j < 6; j++) {
        const float4 gv = *(const float4*)&gb2[pxs[j] * 36 + k4 * 4];
        a0[j] = fma4(u0, gv, a0[j]); a1[j] = fma4(u1, gv, a1[j]);
        a2[j] = fma4(u2, gv, a2[j]); a3[j] = fma4(u3, gv, a3[j]);
      }
    }
    __syncthreads();   // sb2/gb2 dead; hrow will overwrite region R
    const float bo0 = bo[oc0], bo1 = bo[oc0 + 1], bo2 = bo[oc0 + 2], bo3 = bo[oc0 + 3];
    const int jmax = (q == 0) ? 6 : 5;   // px=80 write must be unique
    for (int j = 0; j < jmax; j++) {
      const int px = pxs[j];
      const int y = px / 9, xx = px - y * 9;
      const int ro = y * 12 + xx;
      const float4 hv = *(const float4*)&h2[px * 68 + oc0];
      hrow[(oc0 + 0) * 108 + ro] = lrelu(hv.x + a0[j] + bo0);
      hrow[(oc0 + 1) * 108 + ro] = lrelu(hv.y + a1[j] + bo1);
      hrow[(oc0 + 2) * 108 + ro] = lrelu(hv.z + a2[j] + bo2);
      hrow[(oc0 + 3) * 108 + ro] = lrelu(hv.w + a3[j] + bo3);
    }
  }
  __syncthreads();

  // ---- stage 5: conv2 64->32 3x3, 2-oc x 7-x blocking, K split in 2 halves ----
  {
    const int ocp = t & 15, yy = (t >> 4) & 7, ich = t >> 7;
    const int oc0 = ocp * 2;
    float a0[7] = {0,0,0,0,0,0,0}, a1[7] = {0,0,0,0,0,0,0};
    if (yy < 7) {
      const float* w20 = &w2[(oc0 * 64 + ich * 32) * 9];
      const float* w21 = w20 + 576;
      for (int ic = 0; ic < 32; ic++) {
        const int hb = (ich * 32 + ic) * 108 + yy * 12;
        const float* wr0 = &w20[ic * 9];
        const float* wr1 = &w21[ic * 9];
#pragma unroll
        for (int ky = 0; ky < 3; ky++) {
          const float4* rp = (const float4*)&hrow[hb + ky * 12];
          const float4 ra = rp[0], rb = rp[1], rc = rp[2];
          const float row[12] = {ra.x, ra.y, ra.z, ra.w, rb.x, rb.y, rb.z, rb.w,
                                 rc.x, rc.y, rc.z, rc.w};
          const float w00 = wr0[ky * 3 + 0], w01 = wr0[ky * 3 + 1], w02 = wr0[ky * 3 + 2];
          const float w10 = wr1[ky * 3 + 0], w11 = wr1[ky * 3 + 1], w12 = wr1[ky * 3 + 2];
#pragma unroll
          for (int xx = 0; xx < 7; xx++) {
            a0[xx] = fmaf(row[xx], w00, fmaf(row[xx + 1], w01, fmaf(row[xx + 2], w02, a0[xx])));
            a1[xx] = fmaf(row[xx], w10, fmaf(row[xx + 1], w11, fmaf(row[xx + 2], w12, a1[xx])));
          }
        }
      }
      if (ich == 1) {
        float* cp = &c2p[(yy * 16 + ocp) * 14];
#pragma unroll
        for (int xx = 0; xx < 7; xx++) { cp[xx] = a0[xx]; cp[7 + xx] = a1[xx]; }
      }
    }
    __syncthreads();
    if (ich == 0 && yy < 7) {
      const float* cp = &c2p[(yy * 16 + ocp) * 14];
      const float bv0 = b2[oc0], bv1 = b2[oc0 + 1];
#pragma unroll
      for (int xx = 0; xx < 7; xx++) {
        c2s[oc0 * 56 + yy * 8 + xx]       = lrelu(a0[xx] + cp[xx] + bv0);
        c2s[(oc0 + 1) * 56 + yy * 8 + xx] = lrelu(a1[xx] + cp[7 + xx] + bv1);
      }
    }
  }
  __syncthreads();

  // ---- stage 6: conv3 32->8 3x3, K split in 8 groups of 4 ic ----
  {
    const int px = t & 31, ic8 = t >> 5;
    if (px < 25) {
      const int y = px / 5, xx = px - y * 5;
      float p[8] = {0,0,0,0,0,0,0,0};
      for (int i = 0; i < 4; i++) {
        const int icg = ic8 * 4 + i;
#pragma unroll
        for (int ky = 0; ky < 3; ky++) {
          const int base = icg * 56 + (y + ky) * 8 + xx;
          const float r0 = c2s[base], r1 = c2s[base + 1], r2 = c2s[base + 2];
#pragma unroll
          for (int oc = 0; oc < 8; oc++) {
            const float* wr = &w3[(oc * 32 + icg) * 9 + ky * 3];
            p[oc] = fmaf(r0, wr[0], fmaf(r1, wr[1], fmaf(r2, wr[2], p[oc])));
          }
        }
      }
      float* wpp = &p6[px * 64 + ic8 * 8];
#pragma unroll
      for (int oc = 0; oc < 8; oc++) wpp[oc] = p[oc];
    }
  }
  __syncthreads();
  if (t < 200) {
    const int oc = t & 7, px = t >> 3;
    float s = b3[oc];
    const float* rp = &p6[px * 64 + oc];
#pragma unroll
    for (int g = 0; g < 8; g++) s += rp[g * 8];
    c3s[oc * 25 + px] = lrelu(s);
  }
  __syncthreads();

  // ---- stage 7: dense 200->64, 4 chunks (56/56/56/32), float4 ----
  {
    const int o = t & 63, chunk = t >> 6;   // chunk == wave index
    const int start = chunk * 56;
    const int cnt = (chunk == 3) ? 8 : 14;
    const float4* wr4 = (const float4*)&dw1[o * 200 + start];
    const float4* cr4 = (const float4*)&c3s[start];
    float acc = 0.f;
    for (int i = 0; i < cnt; i++) {
      const float4 wv = wr4[i], cv = cr4[i];
      acc += wv.x * cv.x + wv.y * cv.y + wv.z * cv.z + wv.w * cv.w;
    }
    d1p[chunk * 64 + o] = acc;
  }
  __syncthreads();
  if (t < 64) d1[t] = lrelu(d1p[t] + d1p[64 + t] + d1p[128 + t] + d1p[192 + t] + db1[t]);
  __syncthreads();

  // ---- stage 8: dense 64->32 ----
  if (t < 32) {
    float acc = db2[t];
    const float4* wr = (const float4*)&dw2[t * 64];
    const float4* dr = (const float4*)d1;
#pragma unroll
    for (int i = 0; i < 16; i++) acc = fma4(wr[i], dr[i], acc);
    d2[t] = lrelu(acc);
  }
  __syncthreads();

  // ---- stage 9: dense 32->16 ----
  if (t < 16) {
    float acc = db3[t];
    const float4* wr = (const float4*)&dw3[t * 32];
    const float4* dr = (const float4*)d2;
#pragma unroll
    for (int i = 0; i < 8; i++) acc = fma4(wr[i], dr[i], acc);
    d3[t] = lrelu(acc);
  }
  __syncthreads();

  // ---- stage 10: dense 16->8 ----
  if (t < 8) {
    float acc = db4[t];
    const float4* wr = (const float4*)&dw4[t * 16];
    const float4* dr = (const float4*)d3;
#pragma unroll
    for (int i = 0; i < 4; i++) acc = fma4(wr[i], dr[i], acc);
    d4[t] = lrelu(acc);
  }
  __syncthreads();

  // ---- stage 11: dense 8->2 ----
  if (t < 2) {
    float acc = db5[t];
    const float4* wr = (const float4*)&dw5[t * 8];
    const float4* dr = (const float4*)d4;
#pragma unroll
    for (int i = 0; i < 2; i++) acc = fma4(wr[i], dr[i], acc);
    out[(size_t)b * 2 + t] = acc;
  }
}

extern "C" void kernel_launch(void* const* d_in, const int* in_sizes, int n_in,
                              void* d_out, int out_size, void* d_ws, size_t ws_size,
                              hipStream_t stream) {
  const float* x   = (const float*)d_in[0];
  const float* w1  = (const float*)d_in[1];
  const float* b1  = (const float*)d_in[2];
  const float* wt  = (const float*)d_in[3];
  const float* bt  = (const float*)d_in[4];
  const float* wp  = (const float*)d_in[5];
  const float* bp  = (const float*)d_in[6];
  const float* wg  = (const float*)d_in[7];
  const float* bg  = (const float*)d_in[8];
  const float* wo  = (const float*)d_in[9];
  const float* bo  = (const float*)d_in[10];
  const float* w2  = (const float*)d_in[11];
  const float* b2  = (const float*)d_in[12];
  const float* w3  = (const float*)d_in[13];
  const float* b3  = (const float*)d_in[14];
  const float* dw1 = (const float*)d_in[15];
  const float* db1 = (const float*)d_in[16];
  const float* dw2 = (const float*)d_in[17];
  const float* db2 = (const float*)d_in[18];
  const float* dw3 = (const float*)d_in[19];
  const float* db3 = (const float*)d_in[20];
  const float* dw4 = (const float*)d_in[21];
  const float* db4 = (const float*)d_in[22];
  const float* dw5 = (const float*)d_in[23];
  const float* db5 = (const float*)d_in[24];

  int B = in_sizes[0] / 121;
  braggnn_fused<<<B, 256, 0, stream>>>(
      x, w1, b1, wt, bt, wp, bp, wg, bg, wo, bo, w2, b2, w3, b3,
      dw1, db1, dw2, db2, dw3, db3, dw4, db4, dw5, db5,
      (float*)d_out);
}

// Round 4
// 1853.393 us; speedup vs baseline: 1.0968x; 1.0968x over previous
//
#include <hip/hip_runtime.h>

#define NEG 0.01f
__device__ __forceinline__ float lrelu(float v){ return v >= 0.f ? v : NEG * v; }

__device__ __forceinline__ float fma4(float4 wv, float4 hv, float acc) {
  return fmaf(wv.x, hv.x, fmaf(wv.y, hv.y, fmaf(wv.z, hv.z, fmaf(wv.w, hv.w, acc))));
}

// LDS plan (48.5 KB total -> 3 blocks/CU):
// Region R (6912 floats): xs@0(121) ; sb2@0 [81][36], gb2@2916 [81][36] ; hrow@0 [64][9][12]
// Region H (5508 floats): h2@0 [81][68] ch-major ; then c2s@0 [32][7][8], c3s@1792(200),
//   scratch@1992: c2p(1568) / p6(1600) / d1p(256)+d1(64)+d2(32)+d3(16)+d4(8)
// NOTE: every local array must be indexed only by compile-time constants after
// unrolling — a single runtime-bound loop over a register array demotes it to
// scratch (R2: 810 MB HBM writes, +20% dur). Stage-4 epilogue is the hot spot.
__global__ __launch_bounds__(256, 3) void braggnn_fused(
    const float* __restrict__ x,
    const float* __restrict__ w1, const float* __restrict__ b1,
    const float* __restrict__ wt, const float* __restrict__ bt,
    const float* __restrict__ wp, const float* __restrict__ bp,
    const float* __restrict__ wg, const float* __restrict__ bg,
    const float* __restrict__ wo, const float* __restrict__ bo,
    const float* __restrict__ w2, const float* __restrict__ b2,
    const float* __restrict__ w3, const float* __restrict__ b3,
    const float* __restrict__ dw1, const float* __restrict__ db1,
    const float* __restrict__ dw2, const float* __restrict__ db2,
    const float* __restrict__ dw3, const float* __restrict__ db3,
    const float* __restrict__ dw4, const float* __restrict__ db4,
    const float* __restrict__ dw5, const float* __restrict__ db5,
    float* __restrict__ out)
{
  const int b = blockIdx.x;
  const int t = threadIdx.x;

  __shared__ __align__(16) float R[6912];
  __shared__ __align__(16) float H[5508];

  float* xs   = R;
  float* sb2  = R;            // [81][36]
  float* gb2  = R + 2916;     // [81][36]
  float* hrow = R;            // [64][9][12]
  float* h2   = H;            // [81][68]
  float* c2s  = H;            // [32][7][8]
  float* c3s  = H + 1792;     // 200
  float* c2p  = H + 1992;     // 112*14
  float* p6   = H + 1992;     // 25*64
  float* d1p  = H + 1992;     // 256
  float* d1   = H + 1992 + 256;
  float* d2   = d1 + 64;
  float* d3   = d2 + 32;
  float* d4   = d3 + 16;

  // ---- stage 0: load 11x11 patch ----
  if (t < 121) xs[t] = x[(size_t)b * 121 + t];
  __syncthreads();

  // ---- stage 1: conv1 1->64 3x3 -> h2[px][oc] (ch-major, stride 68), no act ----
  {
    const int oc = t & 63, pg = t >> 6;
    float wreg[9];
#pragma unroll
    for (int i = 0; i < 9; i++) wreg[i] = w1[oc * 9 + i];
    const float bv = b1[oc];
    for (int px = pg; px < 81; px += 4) {
      const int y = px / 9, xx = px - y * 9;
      const float* xr = &xs[y * 11 + xx];
      float a = bv;
#pragma unroll
      for (int ky = 0; ky < 3; ky++)
#pragma unroll
        for (int kx = 0; kx < 3; kx++)
          a = fmaf(xr[ky * 11 + kx], wreg[ky * 3 + kx], a);
      h2[px * 68 + oc] = a;
    }
  }
  __syncthreads();

  // ---- stage 2: theta/phi/g 1x1 (64->32), 2-oc x 6-px blocking, b128 channel reads ----
  {
    const int ocp = t >> 4, q = t & 15;
    const int oc0 = ocp * 2;
    int pxs[6];
#pragma unroll
    for (int j = 0; j < 6; j++) { int p = q + 16 * j; pxs[j] = (p > 80) ? 80 : p; }
    float aT0[6] = {0,0,0,0,0,0}, aT1[6] = {0,0,0,0,0,0};
    float aP0[6] = {0,0,0,0,0,0}, aP1[6] = {0,0,0,0,0,0};
    float aG0[6] = {0,0,0,0,0,0}, aG1[6] = {0,0,0,0,0,0};
    const float4* wt4 = (const float4*)wt;
    const float4* wp4 = (const float4*)wp;
    const float4* wg4 = (const float4*)wg;
    const int r0 = oc0 * 16, r1 = r0 + 16;
#pragma unroll 4
    for (int k4 = 0; k4 < 16; k4++) {
      const float4 wT0 = wt4[r0 + k4], wT1 = wt4[r1 + k4];
      const float4 wP0 = wp4[r0 + k4], wP1 = wp4[r1 + k4];
      const float4 wG0 = wg4[r0 + k4], wG1 = wg4[r1 + k4];
#pragma unroll
      for (int j = 0; j < 6; j++) {
        const float4 hv = *(const float4*)&h2[pxs[j] * 68 + k4 * 4];
        aT0[j] = fma4(wT0, hv, aT0[j]); aT1[j] = fma4(wT1, hv, aT1[j]);
        aP0[j] = fma4(wP0, hv, aP0[j]); aP1[j] = fma4(wP1, hv, aP1[j]);
        aG0[j] = fma4(wG0, hv, aG0[j]); aG1[j] = fma4(wG1, hv, aG1[j]);
      }
    }
    const float bT0 = bt[oc0], bT1 = bt[oc0 + 1];
    const float bP0 = bp[oc0], bP1 = bp[oc0 + 1];
    const float bG0 = bg[oc0], bG1 = bg[oc0 + 1];
#pragma unroll
    for (int j = 0; j < 6; j++) {
      const int base = pxs[j] * 36 + oc0;
      float2 sv, gv;
      sv.x = (aT0[j] + bT0) * (aP0[j] + bP0);
      sv.y = (aT1[j] + bT1) * (aP1[j] + bP1);
      gv.x = aG0[j] + bG0;
      gv.y = aG1[j] + bG1;
      *(float2*)&sb2[base] = sv;   // duplicate px=80 writes carry identical values
      *(float2*)&gb2[base] = gv;
    }
  }
  __syncthreads();

  // ---- stage 3: softmax over W (9), scale gb2 in place ----
  for (int r = t; r < 288; r += 256) {
    const int oc = r & 31, y = r >> 5;
    const int base = y * 9 * 36 + oc;
    float v[9]; float m = -1e30f;
#pragma unroll
    for (int k = 0; k < 9; k++) { v[k] = sb2[base + k * 36]; m = fmaxf(m, v[k]); }
    float s = 0.f;
#pragma unroll
    for (int k = 0; k < 9; k++) { v[k] = __expf(v[k] - m); s += v[k]; }
    const float inv = 1.f / s;
#pragma unroll
    for (int k = 0; k < 9; k++) gb2[base + k * 36] *= v[k] * inv;
  }
  __syncthreads();

  // ---- stage 4: wo 1x1 (32->64) + residual + lrelu; transpose to hrow ----
  {
    const int ocq = t >> 4, q = t & 15;
    const int oc0 = ocq * 4;
    int pxs[6];
#pragma unroll
    for (int j = 0; j < 6; j++) { int p = q + 16 * j; pxs[j] = (p > 80) ? 80 : p; }
    float a0[6] = {0,0,0,0,0,0}, a1[6] = {0,0,0,0,0,0};
    float a2[6] = {0,0,0,0,0,0}, a3[6] = {0,0,0,0,0,0};
    const float4* wo4 = (const float4*)wo;
#pragma unroll 4
    for (int k4 = 0; k4 < 8; k4++) {
      const float4 u0 = wo4[(oc0 + 0) * 8 + k4];
      const float4 u1 = wo4[(oc0 + 1) * 8 + k4];
      const float4 u2 = wo4[(oc0 + 2) * 8 + k4];
      const float4 u3 = wo4[(oc0 + 3) * 8 + k4];
#pragma unroll
      for (int j = 0; j < 6; j++) {
        const float4 gv = *(const float4*)&gb2[pxs[j] * 36 + k4 * 4];
        a0[j] = fma4(u0, gv, a0[j]); a1[j] = fma4(u1, gv, a1[j]);
        a2[j] = fma4(u2, gv, a2[j]); a3[j] = fma4(u3, gv, a3[j]);
      }
    }
    __syncthreads();   // sb2/gb2 dead; hrow will overwrite region R
    const float bo0 = bo[oc0], bo1 = bo[oc0 + 1], bo2 = bo[oc0 + 2], bo3 = bo[oc0 + 3];
    // FULLY UNROLLED j with per-iteration predicate: keeps a0..a3/pxs in VGPRs.
    // (Runtime jmax here demoted these arrays to scratch -> 810 MB HBM traffic.)
#pragma unroll
    for (int j = 0; j < 6; j++) {
      if (q + 16 * j <= 80) {          // unique-write predicate (px=80 only from q==0,j==5)
        const int px = pxs[j];
        const int y = px / 9, xx = px - y * 9;
        const int ro = y * 12 + xx;
        const float4 hv = *(const float4*)&h2[px * 68 + oc0];
        hrow[(oc0 + 0) * 108 + ro] = lrelu(hv.x + a0[j] + bo0);
        hrow[(oc0 + 1) * 108 + ro] = lrelu(hv.y + a1[j] + bo1);
        hrow[(oc0 + 2) * 108 + ro] = lrelu(hv.z + a2[j] + bo2);
        hrow[(oc0 + 3) * 108 + ro] = lrelu(hv.w + a3[j] + bo3);
      }
    }
  }
  __syncthreads();

  // ---- stage 5: conv2 64->32 3x3, 2-oc x 7-x blocking, K split in 2 halves ----
  {
    const int ocp = t & 15, yy = (t >> 4) & 7, ich = t >> 7;
    const int oc0 = ocp * 2;
    float a0[7] = {0,0,0,0,0,0,0}, a1[7] = {0,0,0,0,0,0,0};
    if (yy < 7) {
      const float* w20 = &w2[(oc0 * 64 + ich * 32) * 9];
      const float* w21 = w20 + 576;
      for (int ic = 0; ic < 32; ic++) {
        const int hb = (ich * 32 + ic) * 108 + yy * 12;
        const float* wr0 = &w20[ic * 9];
        const float* wr1 = &w21[ic * 9];
#pragma unroll
        for (int ky = 0; ky < 3; ky++) {
          const float4* rp = (const float4*)&hrow[hb + ky * 12];
          const float4 ra = rp[0], rb = rp[1], rc = rp[2];
          const float row[12] = {ra.x, ra.y, ra.z, ra.w, rb.x, rb.y, rb.z, rb.w,
                                 rc.x, rc.y, rc.z, rc.w};
          const float w00 = wr0[ky * 3 + 0], w01 = wr0[ky * 3 + 1], w02 = wr0[ky * 3 + 2];
          const float w10 = wr1[ky * 3 + 0], w11 = wr1[ky * 3 + 1], w12 = wr1[ky * 3 + 2];
#pragma unroll
          for (int xx = 0; xx < 7; xx++) {
            a0[xx] = fmaf(row[xx], w00, fmaf(row[xx + 1], w01, fmaf(row[xx + 2], w02, a0[xx])));
            a1[xx] = fmaf(row[xx], w10, fmaf(row[xx + 1], w11, fmaf(row[xx + 2], w12, a1[xx])));
          }
        }
      }
      if (ich == 1) {
        float* cp = &c2p[(yy * 16 + ocp) * 14];
#pragma unroll
        for (int xx = 0; xx < 7; xx++) { cp[xx] = a0[xx]; cp[7 + xx] = a1[xx]; }
      }
    }
    __syncthreads();
    if (ich == 0 && yy < 7) {
      const float* cp = &c2p[(yy * 16 + ocp) * 14];
      const float bv0 = b2[oc0], bv1 = b2[oc0 + 1];
#pragma unroll
      for (int xx = 0; xx < 7; xx++) {
        c2s[oc0 * 56 + yy * 8 + xx]       = lrelu(a0[xx] + cp[xx] + bv0);
        c2s[(oc0 + 1) * 56 + yy * 8 + xx] = lrelu(a1[xx] + cp[7 + xx] + bv1);
      }
    }
  }
  __syncthreads();

  // ---- stage 6: conv3 32->8 3x3, K split in 8 groups of 4 ic ----
  {
    const int px = t & 31, ic8 = t >> 5;
    if (px < 25) {
      const int y = px / 5, xx = px - y * 5;
      float p[8] = {0,0,0,0,0,0,0,0};
#pragma unroll
      for (int i = 0; i < 4; i++) {
        const int icg = ic8 * 4 + i;
#pragma unroll
        for (int ky = 0; ky < 3; ky++) {
          const int base = icg * 56 + (y + ky) * 8 + xx;
          const float r0 = c2s[base], r1 = c2s[base + 1], r2 = c2s[base + 2];
#pragma unroll
          for (int oc = 0; oc < 8; oc++) {
            const float* wr = &w3[(oc * 32 + icg) * 9 + ky * 3];
            p[oc] = fmaf(r0, wr[0], fmaf(r1, wr[1], fmaf(r2, wr[2], p[oc])));
          }
        }
      }
      float* wpp = &p6[px * 64 + ic8 * 8];
#pragma unroll
      for (int oc = 0; oc < 8; oc++) wpp[oc] = p[oc];
    }
  }
  __syncthreads();
  if (t < 200) {
    const int oc = t & 7, px = t >> 3;
    float s = b3[oc];
    const float* rp = &p6[px * 64 + oc];
#pragma unroll
    for (int g = 0; g < 8; g++) s += rp[g * 8];
    c3s[oc * 25 + px] = lrelu(s);
  }
  __syncthreads();

  // ---- stage 7: dense 200->64, 4 chunks (56/56/56/32), float4 ----
  {
    const int o = t & 63, chunk = t >> 6;
    const int start = chunk * 56;
    const int cnt = (chunk == 3) ? 8 : 14;
    const float4* wr4 = (const float4*)&dw1[o * 200 + start];
    const float4* cr4 = (const float4*)&c3s[start];
    float acc = 0.f;
    for (int i = 0; i < cnt; i++) {       // runtime bound OK: indexes memory, not reg arrays
      const float4 wv = wr4[i], cv = cr4[i];
      acc += wv.x * cv.x + wv.y * cv.y + wv.z * cv.z + wv.w * cv.w;
    }
    d1p[chunk * 64 + o] = acc;
  }
  __syncthreads();
  if (t < 64) d1[t] = lrelu(d1p[t] + d1p[64 + t] + d1p[128 + t] + d1p[192 + t] + db1[t]);
  __syncthreads();

  // ---- stage 8: dense 64->32 ----
  if (t < 32) {
    float acc = db2[t];
    const float4* wr = (const float4*)&dw2[t * 64];
    const float4* dr = (const float4*)d1;
#pragma unroll
    for (int i = 0; i < 16; i++) acc = fma4(wr[i], dr[i], acc);
    d2[t] = lrelu(acc);
  }
  __syncthreads();

  // ---- stage 9: dense 32->16 ----
  if (t < 16) {
    float acc = db3[t];
    const float4* wr = (const float4*)&dw3[t * 32];
    const float4* dr = (const float4*)d2;
#pragma unroll
    for (int i = 0; i < 8; i++) acc = fma4(wr[i], dr[i], acc);
    d3[t] = lrelu(acc);
  }
  __syncthreads();

  // ---- stage 10: dense 16->8 ----
  if (t < 8) {
    float acc = db4[t];
    const float4* wr = (const float4*)&dw4[t * 16];
    const float4* dr = (const float4*)d3;
#pragma unroll
    for (int i = 0; i < 4; i++) acc = fma4(wr[i], dr[i], acc);
    d4[t] = lrelu(acc);
  }
  __syncthreads();

  // ---- stage 11: dense 8->2 ----
  if (t < 2) {
    float acc = db5[t];
    const float4* wr = (const float4*)&dw5[t * 8];
    const float4* dr = (const float4*)d4;
#pragma unroll
    for (int i = 0; i < 2; i++) acc = fma4(wr[i], dr[i], acc);
    out[(size_t)b * 2 + t] = acc;
  }
}

extern "C" void kernel_launch(void* const* d_in, const int* in_sizes, int n_in,
                              void* d_out, int out_size, void* d_ws, size_t ws_size,
                              hipStream_t stream) {
  const float* x   = (const float*)d_in[0];
  const float* w1  = (const float*)d_in[1];
  const float* b1  = (const float*)d_in[2];
  const float* wt  = (const float*)d_in[3];
  const float* bt  = (const float*)d_in[4];
  const float* wp  = (const float*)d_in[5];
  const float* bp  = (const float*)d_in[6];
  const float* wg  = (const float*)d_in[7];
  const float* bg  = (const float*)d_in[8];
  const float* wo  = (const float*)d_in[9];
  const float* bo  = (const float*)d_in[10];
  const float* w2  = (const float*)d_in[11];
  const float* b2  = (const float*)d_in[12];
  const float* w3  = (const float*)d_in[13];
  const float* b3  = (const float*)d_in[14];
  const float* dw1 = (const float*)d_in[15];
  const float* db1 = (const float*)d_in[16];
  const float* dw2 = (const float*)d_in[17];
  const float* db2 = (const float*)d_in[18];
  const float* dw3 = (const float*)d_in[19];
  const float* db3 = (const float*)d_in[20];
  const float* dw4 = (const float*)d_in[21];
  const float* db4 = (const float*)d_in[22];
  const float* dw5 = (const float*)d_in[23];
  const float* db5 = (const float*)d_in[24];

  int B = in_sizes[0] / 121;
  braggnn_fused<<<B, 256, 0, stream>>>(
      x, w1, b1, wt, bt, wp, bp, wg, bg, wo, bo, w2, b2, w3, b3,
      dw1, db1, dw2, db2, dw3, db3, dw4, db4, dw5, db5,
      (float*)d_out);
}

// Round 5
// 1461.212 us; speedup vs baseline: 1.3911x; 1.2684x over previous
//
#include <hip/hip_runtime.h>

#define NEG 0.01f
__device__ __forceinline__ float lrelu(float v){ return v >= 0.f ? v : NEG * v; }

__device__ __forceinline__ float fma4(float4 wv, float4 hv, float acc) {
  return fmaf(wv.x, hv.x, fmaf(wv.y, hv.y, fmaf(wv.z, hv.z, fmaf(wv.w, hv.w, acc))));
}

// ---- LDS plan: single arena S[8896] (35584 B -> 4 blocks/CU, 16 waves) ----
// Phase A (stages 0-4a): XS@0(121) | GB2@128(81x36=2916) | H2@3072(81x68=5508)
// Phase B (4b-5):        HROW@128(64x108=6912)  [aliases GB2+H2 head; residual
//                        pre-read into regs before the mid-stage-4 sync]
//                        C2S@7040(32x57=1824)   [aliases dead H2 tail]
// Phase C (6+):          P6@0(1600) C3S@1664(200) D1P@1920(256) D1@2176 D2@2240
//                        D3@2272 D4@2288        [aliases dead HROW head]
// RULES (R2 lesson): no runtime-bound loop may index a register array — full
// unroll + per-iteration predicate only. (Violating this cost 810 MB of HBM
// scratch traffic.)
#define XS   0
#define GB2  128
#define H2   3072
#define HROW 128
#define C2S  7040
#define P6   0
#define C3S  1664
#define D1P  1920
#define D1   2176
#define D2   2240
#define D3   2272
#define D4   2288

// repack w2 [oc][ic][9] -> pw2 [ic][oc][12] (pad 3) for coalesced float4 loads
__global__ void repack_w2(const float* __restrict__ w2, float* __restrict__ pw2) {
  int idx = blockIdx.x * 256 + threadIdx.x;
  for (int i = idx; i < 64 * 32 * 12; i += gridDim.x * 256) {
    int s = i % 12, rest = i / 12, oc = rest & 31, ic = rest >> 5;
    pw2[i] = (s < 9) ? w2[(oc * 64 + ic) * 9 + s] : 0.f;
  }
}

__global__ __launch_bounds__(256, 4) void braggnn_fused(
    const float* __restrict__ x,
    const float* __restrict__ w1, const float* __restrict__ b1,
    const float* __restrict__ wt, const float* __restrict__ bt,
    const float* __restrict__ wp, const float* __restrict__ bp,
    const float* __restrict__ wg, const float* __restrict__ bg,
    const float* __restrict__ wo, const float* __restrict__ bo,
    const float* __restrict__ pw2, const float* __restrict__ b2,
    const float* __restrict__ w3, const float* __restrict__ b3,
    const float* __restrict__ dw1, const float* __restrict__ db1,
    const float* __restrict__ dw2, const float* __restrict__ db2,
    const float* __restrict__ dw3, const float* __restrict__ db3,
    const float* __restrict__ dw4, const float* __restrict__ db4,
    const float* __restrict__ dw5, const float* __restrict__ db5,
    float* __restrict__ out)
{
  const int b = blockIdx.x;
  const int t = threadIdx.x;

  __shared__ __align__(16) float S[8896];

  // ---- stage 0: load 11x11 patch ----
  if (t < 121) S[XS + t] = x[(size_t)b * 121 + t];
  __syncthreads();

  // ---- stage 1: conv1 1->64 3x3 -> H2[px][oc] ch-major stride 68 (no act) ----
  {
    const int oc = t & 63, pg = t >> 6;
    float wreg[9];
#pragma unroll
    for (int i = 0; i < 9; i++) wreg[i] = w1[oc * 9 + i];
    const float bv = b1[oc];
    for (int px = pg; px < 81; px += 4) {
      const int y = px / 9, xx = px - y * 9;
      const float* xr = &S[XS + y * 11 + xx];
      float a = bv;
#pragma unroll
      for (int ky = 0; ky < 3; ky++)
#pragma unroll
        for (int kx = 0; kx < 3; kx++)
          a = fmaf(xr[ky * 11 + kx], wreg[ky * 3 + kx], a);
      S[H2 + px * 68 + oc] = a;
    }
  }
  __syncthreads();

  // ---- stage 2 (+3 fused): theta/phi/g + softmax per row (oc,y), 288 rows ----
  {
    const float4* wt4 = (const float4*)wt;
    const float4* wp4 = (const float4*)wp;
    const float4* wg4 = (const float4*)wg;
    auto row_job = [&](int r) {
      const int oc = r & 31, y = r >> 5;
      float th[9] = {0,0,0,0,0,0,0,0,0};
      float ph[9] = {0,0,0,0,0,0,0,0,0};
      float gg[9] = {0,0,0,0,0,0,0,0,0};
      const int hb = H2 + y * 9 * 68;
#pragma unroll 2
      for (int k4 = 0; k4 < 16; k4++) {
        const float4 wT = wt4[oc * 16 + k4];
        const float4 wP = wp4[oc * 16 + k4];
        const float4 wG = wg4[oc * 16 + k4];
#pragma unroll
        for (int xx = 0; xx < 9; xx++) {
          const float4 hv = *(const float4*)&S[hb + xx * 68 + k4 * 4];
          th[xx] = fma4(wT, hv, th[xx]);
          ph[xx] = fma4(wP, hv, ph[xx]);
          gg[xx] = fma4(wG, hv, gg[xx]);
        }
      }
      const float bT = bt[oc], bP = bp[oc], bG = bg[oc];
      float sc[9]; float m = -1e30f;
#pragma unroll
      for (int xx = 0; xx < 9; xx++) {
        sc[xx] = (th[xx] + bT) * (ph[xx] + bP);
        m = fmaxf(m, sc[xx]);
      }
      float sum = 0.f;
#pragma unroll
      for (int xx = 0; xx < 9; xx++) { sc[xx] = __expf(sc[xx] - m); sum += sc[xx]; }
      const float inv = 1.f / sum;
#pragma unroll
      for (int xx = 0; xx < 9; xx++)
        S[GB2 + (y * 9 + xx) * 36 + oc] = (gg[xx] + bG) * (sc[xx] * inv);
    };
    row_job(t);
    if (t < 32) row_job(t + 256);
  }
  __syncthreads();

  // ---- stage 4: wo 1x1 (32->64) + residual + lrelu -> HROW [oc][9][12] ----
  {
    const int ocq = t >> 4, q = t & 15;
    const int oc0 = ocq * 4;
    int pxs[6];
#pragma unroll
    for (int j = 0; j < 6; j++) { int p = q + 16 * j; pxs[j] = (p > 80) ? 80 : p; }
    float a0[6] = {0,0,0,0,0,0}, a1[6] = {0,0,0,0,0,0};
    float a2[6] = {0,0,0,0,0,0}, a3[6] = {0,0,0,0,0,0};
    const float4* wo4 = (const float4*)wo;
#pragma unroll 4
    for (int k4 = 0; k4 < 8; k4++) {
      const float4 u0 = wo4[(oc0 + 0) * 8 + k4];
      const float4 u1 = wo4[(oc0 + 1) * 8 + k4];
      const float4 u2 = wo4[(oc0 + 2) * 8 + k4];
      const float4 u3 = wo4[(oc0 + 3) * 8 + k4];
#pragma unroll
      for (int j = 0; j < 6; j++) {
        const float4 gv = *(const float4*)&S[GB2 + pxs[j] * 36 + k4 * 4];
        a0[j] = fma4(u0, gv, a0[j]); a1[j] = fma4(u1, gv, a1[j]);
        a2[j] = fma4(u2, gv, a2[j]); a3[j] = fma4(u3, gv, a3[j]);
      }
    }
    // residual pre-read (H2 dies at the sync; HROW aliases GB2+H2 head)
    float4 hres[6];
#pragma unroll
    for (int j = 0; j < 6; j++)
      hres[j] = *(const float4*)&S[H2 + pxs[j] * 68 + oc0];
    __syncthreads();
    const float bo0 = bo[oc0], bo1 = bo[oc0 + 1], bo2 = bo[oc0 + 2], bo3 = bo[oc0 + 3];
#pragma unroll
    for (int j = 0; j < 6; j++) {
      if (q + 16 * j <= 80) {   // unique-write predicate, compile-time unrolled
        const int px = pxs[j];
        const int y = px / 9, xx = px - y * 9;
        const int ro = y * 12 + xx;
        S[HROW + (oc0 + 0) * 108 + ro] = lrelu(hres[j].x + a0[j] + bo0);
        S[HROW + (oc0 + 1) * 108 + ro] = lrelu(hres[j].y + a1[j] + bo1);
        S[HROW + (oc0 + 2) * 108 + ro] = lrelu(hres[j].z + a2[j] + bo2);
        S[HROW + (oc0 + 3) * 108 + ro] = lrelu(hres[j].w + a3[j] + bo3);
      }
    }
  }
  __syncthreads();

  // ---- stage 5: conv2 64->32 3x3, thread=(oc,yy), full K, packed weights ----
  if (t < 224) {
    const int oc = t & 31, yy = t >> 5;   // 32 oc x 7 rows
    float a[7] = {0,0,0,0,0,0,0};
    const float4* pw4 = (const float4*)pw2;
#pragma unroll 2
    for (int ic = 0; ic < 64; ic++) {
      const float4 f0 = pw4[(ic * 32 + oc) * 3 + 0];
      const float4 f1 = pw4[(ic * 32 + oc) * 3 + 1];
      const float4 f2 = pw4[(ic * 32 + oc) * 3 + 2];
      const int hb = HROW + ic * 108 + yy * 12;
#pragma unroll
      for (int ky = 0; ky < 3; ky++) {
        const float4* rp = (const float4*)&S[hb + ky * 12];
        const float4 ra = rp[0], rb = rp[1], rc = rp[2];
        const float row[12] = {ra.x, ra.y, ra.z, ra.w, rb.x, rb.y, rb.z, rb.w,
                               rc.x, rc.y, rc.z, rc.w};
        float w0, w1v, w2v;
        if (ky == 0)      { w0 = f0.x; w1v = f0.y; w2v = f0.z; }
        else if (ky == 1) { w0 = f0.w; w1v = f1.x; w2v = f1.y; }
        else              { w0 = f1.z; w1v = f1.w; w2v = f2.x; }
#pragma unroll
        for (int xx = 0; xx < 7; xx++)
          a[xx] = fmaf(row[xx], w0,
                  fmaf(row[xx + 1], w1v,
                  fmaf(row[xx + 2], w2v, a[xx])));
      }
    }
    const float bv = b2[oc];
#pragma unroll
    for (int xx = 0; xx < 7; xx++)
      S[C2S + oc * 57 + yy * 8 + xx] = lrelu(a[xx] + bv);
  }
  __syncthreads();

  // ---- stage 6: conv3 32->8 3x3, K split in 8 groups of 4 ic ----
  {
    const int px = t & 31, ic8 = t >> 5;
    if (px < 25) {
      const int y = px / 5, xx = px - y * 5;
      float p[8] = {0,0,0,0,0,0,0,0};
#pragma unroll
      for (int i = 0; i < 4; i++) {
        const int icg = ic8 * 4 + i;
#pragma unroll
        for (int ky = 0; ky < 3; ky++) {
          const int base = C2S + icg * 57 + (y + ky) * 8 + xx;
          const float r0 = S[base], r1 = S[base + 1], r2 = S[base + 2];
#pragma unroll
          for (int oc = 0; oc < 8; oc++) {
            const float* wr = &w3[(oc * 32 + icg) * 9 + ky * 3];
            p[oc] = fmaf(r0, wr[0], fmaf(r1, wr[1], fmaf(r2, wr[2], p[oc])));
          }
        }
      }
      float* wpp = &S[P6 + px * 64 + ic8 * 8];
#pragma unroll
      for (int oc = 0; oc < 8; oc++) wpp[oc] = p[oc];
    }
  }
  __syncthreads();
  if (t < 200) {
    const int oc = t & 7, px = t >> 3;
    float s = b3[oc];
    const float* rp = &S[P6 + px * 64 + oc];
#pragma unroll
    for (int g = 0; g < 8; g++) s += rp[g * 8];
    S[C3S + oc * 25 + px] = lrelu(s);
  }
  __syncthreads();

  // ---- stage 7: dense 200->64, 4 chunks (56/56/56/32), float4 ----
  {
    const int o = t & 63, chunk = t >> 6;
    const int start = chunk * 56;
    const int cnt = (chunk == 3) ? 8 : 14;
    const float4* wr4 = (const float4*)&dw1[o * 200 + start];
    const float4* cr4 = (const float4*)&S[C3S + start];
    float acc = 0.f;
    for (int i = 0; i < cnt; i++) {   // runtime bound OK: memory only
      const float4 wv = wr4[i], cv = cr4[i];
      acc += wv.x * cv.x + wv.y * cv.y + wv.z * cv.z + wv.w * cv.w;
    }
    S[D1P + chunk * 64 + o] = acc;
  }
  __syncthreads();
  if (t < 64)
    S[D1 + t] = lrelu(S[D1P + t] + S[D1P + 64 + t] + S[D1P + 128 + t] +
                      S[D1P + 192 + t] + db1[t]);
  __syncthreads();

  // ---- stage 8: dense 64->32 ----
  if (t < 32) {
    float acc = db2[t];
    const float4* wr = (const float4*)&dw2[t * 64];
    const float4* dr = (const float4*)&S[D1];
#pragma unroll
    for (int i = 0; i < 16; i++) acc = fma4(wr[i], dr[i], acc);
    S[D2 + t] = lrelu(acc);
  }
  __syncthreads();

  // ---- stage 9: dense 32->16 ----
  if (t < 16) {
    float acc = db3[t];
    const float4* wr = (const float4*)&dw3[t * 32];
    const float4* dr = (const float4*)&S[D2];
#pragma unroll
    for (int i = 0; i < 8; i++) acc = fma4(wr[i], dr[i], acc);
    S[D3 + t] = lrelu(acc);
  }
  __syncthreads();

  // ---- stage 10: dense 16->8 ----
  if (t < 8) {
    float acc = db4[t];
    const float4* wr = (const float4*)&dw4[t * 16];
    const float4* dr = (const float4*)&S[D3];
#pragma unroll
    for (int i = 0; i < 4; i++) acc = fma4(wr[i], dr[i], acc);
    S[D4 + t] = lrelu(acc);
  }
  __syncthreads();

  // ---- stage 11: dense 8->2 ----
  if (t < 2) {
    float acc = db5[t];
    const float4* wr = (const float4*)&dw5[t * 8];
    const float4* dr = (const float4*)&S[D4];
#pragma unroll
    for (int i = 0; i < 2; i++) acc = fma4(wr[i], dr[i], acc);
    out[(size_t)b * 2 + t] = acc;
  }
}

extern "C" void kernel_launch(void* const* d_in, const int* in_sizes, int n_in,
                              void* d_out, int out_size, void* d_ws, size_t ws_size,
                              hipStream_t stream) {
  const float* x   = (const float*)d_in[0];
  const float* w1  = (const float*)d_in[1];
  const float* b1  = (const float*)d_in[2];
  const float* wt  = (const float*)d_in[3];
  const float* bt  = (const float*)d_in[4];
  const float* wp  = (const float*)d_in[5];
  const float* bp  = (const float*)d_in[6];
  const float* wg  = (const float*)d_in[7];
  const float* bg  = (const float*)d_in[8];
  const float* wo  = (const float*)d_in[9];
  const float* bo  = (const float*)d_in[10];
  const float* w2  = (const float*)d_in[11];
  const float* b2  = (const float*)d_in[12];
  const float* w3  = (const float*)d_in[13];
  const float* b3  = (const float*)d_in[14];
  const float* dw1 = (const float*)d_in[15];
  const float* db1 = (const float*)d_in[16];
  const float* dw2 = (const float*)d_in[17];
  const float* db2 = (const float*)d_in[18];
  const float* dw3 = (const float*)d_in[19];
  const float* db3 = (const float*)d_in[20];
  const float* dw4 = (const float*)d_in[21];
  const float* db4 = (const float*)d_in[22];
  const float* dw5 = (const float*)d_in[23];
  const float* db5 = (const float*)d_in[24];

  float* pw2 = (float*)d_ws;            // 64*32*12 floats = 98304 B
  repack_w2<<<32, 256, 0, stream>>>(w2, pw2);

  int B = in_sizes[0] / 121;
  braggnn_fused<<<B, 256, 0, stream>>>(
      x, w1, b1, wt, bt, wp, bp, wg, bg, wo, bo, pw2, b2, w3, b3,
      dw1, db1, dw2, db2, dw3, db3, dw4, db4, dw5, db5,
      (float*)d_out);
}

// Round 6
// 1328.162 us; speedup vs baseline: 1.5305x; 1.1002x over previous
//
#include <hip/hip_runtime.h>

#define NEG 0.01f
__device__ __forceinline__ float lrelu(float v){ return v >= 0.f ? v : NEG * v; }

__device__ __forceinline__ float fma4(float4 wv, float4 hv, float acc) {
  return fmaf(wv.x, hv.x, fmaf(wv.y, hv.y, fmaf(wv.z, hv.z, fmaf(wv.w, hv.w, acc))));
}

// ---- LDS plan: single arena S[8896] (35584 B -> 4 blocks/CU, 16 waves) ----
// Phase A (stages 0-4a): XS@0(121) | GB2@128(81x36=2916) | H2@3072(81x68=5508)
// Phase B (4b-5):        HROW@128(64x108=6912)  [aliases GB2+H2 head; residual
//                        pre-read into regs before the mid-stage-4 sync]
//                        C2S@7040(32x57=1824)   [aliases dead H2 tail]
// Phase C (6+):          P6@0(1600) C3S@1664(200) D1P@1920(256) D1@2176 D2@2240
//                        D3@2272 D4@2288        [aliases dead HROW head]
// RULES:
//  (R2) no runtime-bound loop may index a register array — full unroll +
//       per-iteration predicate only (violation = 810 MB scratch traffic).
//  (R5) do NOT tighten __launch_bounds__ to (256,4): the allocator force-caps
//       VGPR at 64 and spills ~19 KB/block (308 MB HBM writes). LDS already
//       caps us at 4 blocks/CU; any VGPR<=128 keeps 16 waves/CU.
#define XS   0
#define GB2  128
#define H2   3072
#define HROW 128
#define C2S  7040
#define P6   0
#define C3S  1664
#define D1P  1920
#define D1   2176
#define D2   2240
#define D3   2272
#define D4   2288

// repack w2 [oc][ic][9] -> pw2 [ic][oc][12] (pad 3) for coalesced float4 loads
__global__ void repack_w2(const float* __restrict__ w2, float* __restrict__ pw2) {
  int idx = blockIdx.x * 256 + threadIdx.x;
  for (int i = idx; i < 64 * 32 * 12; i += gridDim.x * 256) {
    int s = i % 12, rest = i / 12, oc = rest & 31, ic = rest >> 5;
    pw2[i] = (s < 9) ? w2[(oc * 64 + ic) * 9 + s] : 0.f;
  }
}

__global__ __launch_bounds__(256, 3) void braggnn_fused(
    const float* __restrict__ x,
    const float* __restrict__ w1, const float* __restrict__ b1,
    const float* __restrict__ wt, const float* __restrict__ bt,
    const float* __restrict__ wp, const float* __restrict__ bp,
    const float* __restrict__ wg, const float* __restrict__ bg,
    const float* __restrict__ wo, const float* __restrict__ bo,
    const float* __restrict__ pw2, const float* __restrict__ b2,
    const float* __restrict__ w3, const float* __restrict__ b3,
    const float* __restrict__ dw1, const float* __restrict__ db1,
    const float* __restrict__ dw2, const float* __restrict__ db2,
    const float* __restrict__ dw3, const float* __restrict__ db3,
    const float* __restrict__ dw4, const float* __restrict__ db4,
    const float* __restrict__ dw5, const float* __restrict__ db5,
    float* __restrict__ out)
{
  const int b = blockIdx.x;
  const int t = threadIdx.x;

  __shared__ __align__(16) float S[8896];

  // ---- stage 0: load 11x11 patch ----
  if (t < 121) S[XS + t] = x[(size_t)b * 121 + t];
  __syncthreads();

  // ---- stage 1: conv1 1->64 3x3 -> H2[px][oc] ch-major stride 68 (no act) ----
  {
    const int oc = t & 63, pg = t >> 6;
    float wreg[9];
#pragma unroll
    for (int i = 0; i < 9; i++) wreg[i] = w1[oc * 9 + i];
    const float bv = b1[oc];
    for (int px = pg; px < 81; px += 4) {
      const int y = px / 9, xx = px - y * 9;
      const float* xr = &S[XS + y * 11 + xx];
      float a = bv;
#pragma unroll
      for (int ky = 0; ky < 3; ky++)
#pragma unroll
        for (int kx = 0; kx < 3; kx++)
          a = fmaf(xr[ky * 11 + kx], wreg[ky * 3 + kx], a);
      S[H2 + px * 68 + oc] = a;
    }
  }
  __syncthreads();

  // ---- stage 2 (+3 fused): theta/phi/g + softmax per row (oc,y), 288 rows ----
  {
    const float4* wt4 = (const float4*)wt;
    const float4* wp4 = (const float4*)wp;
    const float4* wg4 = (const float4*)wg;
    auto row_job = [&](int r) {
      const int oc = r & 31, y = r >> 5;
      float th[9] = {0,0,0,0,0,0,0,0,0};
      float ph[9] = {0,0,0,0,0,0,0,0,0};
      float gg[9] = {0,0,0,0,0,0,0,0,0};
      const int hb = H2 + y * 9 * 68;
#pragma unroll 2
      for (int k4 = 0; k4 < 16; k4++) {
        const float4 wT = wt4[oc * 16 + k4];
        const float4 wP = wp4[oc * 16 + k4];
        const float4 wG = wg4[oc * 16 + k4];
#pragma unroll
        for (int xx = 0; xx < 9; xx++) {
          const float4 hv = *(const float4*)&S[hb + xx * 68 + k4 * 4];
          th[xx] = fma4(wT, hv, th[xx]);
          ph[xx] = fma4(wP, hv, ph[xx]);
          gg[xx] = fma4(wG, hv, gg[xx]);
        }
      }
      const float bT = bt[oc], bP = bp[oc], bG = bg[oc];
      float sc[9]; float m = -1e30f;
#pragma unroll
      for (int xx = 0; xx < 9; xx++) {
        sc[xx] = (th[xx] + bT) * (ph[xx] + bP);
        m = fmaxf(m, sc[xx]);
      }
      float sum = 0.f;
#pragma unroll
      for (int xx = 0; xx < 9; xx++) { sc[xx] = __expf(sc[xx] - m); sum += sc[xx]; }
      const float inv = 1.f / sum;
#pragma unroll
      for (int xx = 0; xx < 9; xx++)
        S[GB2 + (y * 9 + xx) * 36 + oc] = (gg[xx] + bG) * (sc[xx] * inv);
    };
    row_job(t);
    if (t < 32) row_job(t + 256);
  }
  __syncthreads();

  // ---- stage 4: wo 1x1 (32->64) + residual + lrelu -> HROW [oc][9][12] ----
  {
    const int ocq = t >> 4, q = t & 15;
    const int oc0 = ocq * 4;
    int pxs[6];
#pragma unroll
    for (int j = 0; j < 6; j++) { int p = q + 16 * j; pxs[j] = (p > 80) ? 80 : p; }
    float a0[6] = {0,0,0,0,0,0}, a1[6] = {0,0,0,0,0,0};
    float a2[6] = {0,0,0,0,0,0}, a3[6] = {0,0,0,0,0,0};
    const float4* wo4 = (const float4*)wo;
#pragma unroll 4
    for (int k4 = 0; k4 < 8; k4++) {
      const float4 u0 = wo4[(oc0 + 0) * 8 + k4];
      const float4 u1 = wo4[(oc0 + 1) * 8 + k4];
      const float4 u2 = wo4[(oc0 + 2) * 8 + k4];
      const float4 u3 = wo4[(oc0 + 3) * 8 + k4];
#pragma unroll
      for (int j = 0; j < 6; j++) {
        const float4 gv = *(const float4*)&S[GB2 + pxs[j] * 36 + k4 * 4];
        a0[j] = fma4(u0, gv, a0[j]); a1[j] = fma4(u1, gv, a1[j]);
        a2[j] = fma4(u2, gv, a2[j]); a3[j] = fma4(u3, gv, a3[j]);
      }
    }
    // residual pre-read (H2 dies at the sync; HROW aliases GB2+H2 head)
    float4 hres[6];
#pragma unroll
    for (int j = 0; j < 6; j++)
      hres[j] = *(const float4*)&S[H2 + pxs[j] * 68 + oc0];
    __syncthreads();
    const float bo0 = bo[oc0], bo1 = bo[oc0 + 1], bo2 = bo[oc0 + 2], bo3 = bo[oc0 + 3];
#pragma unroll
    for (int j = 0; j < 6; j++) {
      if (q + 16 * j <= 80) {   // unique-write predicate, compile-time unrolled
        const int px = pxs[j];
        const int y = px / 9, xx = px - y * 9;
        const int ro = y * 12 + xx;
        S[HROW + (oc0 + 0) * 108 + ro] = lrelu(hres[j].x + a0[j] + bo0);
        S[HROW + (oc0 + 1) * 108 + ro] = lrelu(hres[j].y + a1[j] + bo1);
        S[HROW + (oc0 + 2) * 108 + ro] = lrelu(hres[j].z + a2[j] + bo2);
        S[HROW + (oc0 + 3) * 108 + ro] = lrelu(hres[j].w + a3[j] + bo3);
      }
    }
  }
  __syncthreads();

  // ---- stage 5: conv2 64->32 3x3, thread=(oc,yy), full K, packed weights ----
  if (t < 224) {
    const int oc = t & 31, yy = t >> 5;   // 32 oc x 7 rows
    float a[7] = {0,0,0,0,0,0,0};
    const float4* pw4 = (const float4*)pw2;
#pragma unroll 2
    for (int ic = 0; ic < 64; ic++) {
      const float4 f0 = pw4[(ic * 32 + oc) * 3 + 0];
      const float4 f1 = pw4[(ic * 32 + oc) * 3 + 1];
      const float4 f2 = pw4[(ic * 32 + oc) * 3 + 2];
      const int hb = HROW + ic * 108 + yy * 12;
#pragma unroll
      for (int ky = 0; ky < 3; ky++) {
        const float4* rp = (const float4*)&S[hb + ky * 12];
        const float4 ra = rp[0], rb = rp[1], rc = rp[2];
        const float row[12] = {ra.x, ra.y, ra.z, ra.w, rb.x, rb.y, rb.z, rb.w,
                               rc.x, rc.y, rc.z, rc.w};
        float w0, w1v, w2v;
        if (ky == 0)      { w0 = f0.x; w1v = f0.y; w2v = f0.z; }
        else if (ky == 1) { w0 = f0.w; w1v = f1.x; w2v = f1.y; }
        else              { w0 = f1.z; w1v = f1.w; w2v = f2.x; }
#pragma unroll
        for (int xx = 0; xx < 7; xx++)
          a[xx] = fmaf(row[xx], w0,
                  fmaf(row[xx + 1], w1v,
                  fmaf(row[xx + 2], w2v, a[xx])));
      }
    }
    const float bv = b2[oc];
#pragma unroll
    for (int xx = 0; xx < 7; xx++)
      S[C2S + oc * 57 + yy * 8 + xx] = lrelu(a[xx] + bv);
  }
  __syncthreads();

  // ---- stage 6: conv3 32->8 3x3, K split in 8 groups of 4 ic ----
  {
    const int px = t & 31, ic8 = t >> 5;
    if (px < 25) {
      const int y = px / 5, xx = px - y * 5;
      float p[8] = {0,0,0,0,0,0,0,0};
#pragma unroll
      for (int i = 0; i < 4; i++) {
        const int icg = ic8 * 4 + i;
#pragma unroll
        for (int ky = 0; ky < 3; ky++) {
          const int base = C2S + icg * 57 + (y + ky) * 8 + xx;
          const float r0 = S[base], r1 = S[base + 1], r2 = S[base + 2];
#pragma unroll
          for (int oc = 0; oc < 8; oc++) {
            const float* wr = &w3[(oc * 32 + icg) * 9 + ky * 3];
            p[oc] = fmaf(r0, wr[0], fmaf(r1, wr[1], fmaf(r2, wr[2], p[oc])));
          }
        }
      }
      float* wpp = &S[P6 + px * 64 + ic8 * 8];
#pragma unroll
      for (int oc = 0; oc < 8; oc++) wpp[oc] = p[oc];
    }
  }
  __syncthreads();
  if (t < 200) {
    const int oc = t & 7, px = t >> 3;
    float s = b3[oc];
    const float* rp = &S[P6 + px * 64 + oc];
#pragma unroll
    for (int g = 0; g < 8; g++) s += rp[g * 8];
    S[C3S + oc * 25 + px] = lrelu(s);
  }
  __syncthreads();

  // ---- stage 7: dense 200->64, 4 chunks (56/56/56/32), float4 ----
  {
    const int o = t & 63, chunk = t >> 6;
    const int start = chunk * 56;
    const int cnt = (chunk == 3) ? 8 : 14;
    const float4* wr4 = (const float4*)&dw1[o * 200 + start];
    const float4* cr4 = (const float4*)&S[C3S + start];
    float acc = 0.f;
    for (int i = 0; i < cnt; i++) {   // runtime bound OK: memory only
      const float4 wv = wr4[i], cv = cr4[i];
      acc += wv.x * cv.x + wv.y * cv.y + wv.z * cv.z + wv.w * cv.w;
    }
    S[D1P + chunk * 64 + o] = acc;
  }
  __syncthreads();
  if (t < 64)
    S[D1 + t] = lrelu(S[D1P + t] + S[D1P + 64 + t] + S[D1P + 128 + t] +
                      S[D1P + 192 + t] + db1[t]);
  __syncthreads();

  // ---- stage 8: dense 64->32 ----
  if (t < 32) {
    float acc = db2[t];
    const float4* wr = (const float4*)&dw2[t * 64];
    const float4* dr = (const float4*)&S[D1];
#pragma unroll
    for (int i = 0; i < 16; i++) acc = fma4(wr[i], dr[i], acc);
    S[D2 + t] = lrelu(acc);
  }
  __syncthreads();

  // ---- stage 9: dense 32->16 ----
  if (t < 16) {
    float acc = db3[t];
    const float4* wr = (const float4*)&dw3[t * 32];
    const float4* dr = (const float4*)&S[D2];
#pragma unroll
    for (int i = 0; i < 8; i++) acc = fma4(wr[i], dr[i], acc);
    S[D3 + t] = lrelu(acc);
  }
  __syncthreads();

  // ---- stage 10: dense 16->8 ----
  if (t < 8) {
    float acc = db4[t];
    const float4* wr = (const float4*)&dw4[t * 16];
    const float4* dr = (const float4*)&S[D3];
#pragma unroll
    for (int i = 0; i < 4; i++) acc = fma4(wr[i], dr[i], acc);
    S[D4 + t] = lrelu(acc);
  }
  __syncthreads();

  // ---- stage 11: dense 8->2 ----
  if (t < 2) {
    float acc = db5[t];
    const float4* wr = (const float4*)&dw5[t * 8];
    const float4* dr = (const float4*)&S[D4];
#pragma unroll
    for (int i = 0; i < 2; i++) acc = fma4(wr[i], dr[i], acc);
    out[(size_t)b * 2 + t] = acc;
  }
}

extern "C" void kernel_launch(void* const* d_in, const int* in_sizes, int n_in,
                              void* d_out, int out_size, void* d_ws, size_t ws_size,
                              hipStream_t stream) {
  const float* x   = (const float*)d_in[0];
  const float* w1  = (const float*)d_in[1];
  const float* b1  = (const float*)d_in[2];
  const float* wt  = (const float*)d_in[3];
  const float* bt  = (const float*)d_in[4];
  const float* wp  = (const float*)d_in[5];
  const float* bp  = (const float*)d_in[6];
  const float* wg  = (const float*)d_in[7];
  const float* bg  = (const float*)d_in[8];
  const float* wo  = (const float*)d_in[9];
  const float* bo  = (const float*)d_in[10];
  const float* w2  = (const float*)d_in[11];
  const float* b2  = (const float*)d_in[12];
  const float* w3  = (const float*)d_in[13];
  const float* b3  = (const float*)d_in[14];
  const float* dw1 = (const float*)d_in[15];
  const float* db1 = (const float*)d_in[16];
  const float* dw2 = (const float*)d_in[17];
  const float* db2 = (const float*)d_in[18];
  const float* dw3 = (const float*)d_in[19];
  const float* db3 = (const float*)d_in[20];
  const float* dw4 = (const float*)d_in[21];
  const float* db4 = (const float*)d_in[22];
  const float* dw5 = (const float*)d_in[23];
  const float* db5 = (const float*)d_in[24];

  float* pw2 = (float*)d_ws;            // 64*32*12 floats = 98304 B
  repack_w2<<<32, 256, 0, stream>>>(w2, pw2);

  int B = in_sizes[0] / 121;
  braggnn_fused<<<B, 256, 0, stream>>>(
      x, w1, b1, wt, bt, wp, bp, wg, bg, wo, bo, pw2, b2, w3, b3,
      dw1, db1, dw2, db2, dw3, db3, dw4, db4, dw5, db5,
      (float*)d_out);
}